// Round 1
// 157.799 us; speedup vs baseline: 1.0000x; 1.0000x over previous
//
#include <hip/hip_runtime.h>

// Problem constants (fixed by the reference)
#define B_   64
#define S_   512
#define P_   300
#define K_   50
#define MPAD 64      // label dim padded to 64 for MFMA M
#define LDX  344     // x_tile row stride in bf16 elems (16B-aligned rows, bank-balanced)
#define NS   80      // staged s rows per block: 64 + 2*8 halo (5 MFMA N-tiles)
#define LDGS 81      // G-tile LDS row stride in floats (conv phase)

typedef short short8v __attribute__((ext_vector_type(8)));
typedef float float4v __attribute__((ext_vector_type(4)));

__device__ __forceinline__ short f2bf(float f) {
  unsigned u = __builtin_bit_cast(unsigned, f);
  u = (u + 0x7FFFu + ((u >> 16) & 1u)) >> 16;  // RNE
  return (short)u;
}
__device__ __forceinline__ float bf2f(short h) {
  return __builtin_bit_cast(float, ((unsigned)(unsigned short)h) << 16);
}

// ---------------------------------------------------------------------------
// K1: normalize C -> l_hat, pad {l_hat, W2} to 64x320 bf16 (zeros), and pack
// into MFMA A-fragment order so K2's A loads are coalesced 16B/lane.
// apack layout: [(mat*4 + mtile)*10 + kstep][lane][8 bf16]
// grid 80 blocks (mat 2 x mtile 4 x kstep 10) x 64 threads.
// ---------------------------------------------------------------------------
__global__ __launch_bounds__(64) void k1_prep(const float* __restrict__ C,
                                              const float* __restrict__ W2,
                                              short* __restrict__ apack) {
  int bid = blockIdx.x;
  int mat = bid / 40;
  int rem = bid - mat * 40;
  int mt  = rem / 10;
  int ks  = rem - mt * 10;
  int lane = threadIdx.x;
  __shared__ float invn[16];
  if (mat == 0) {
    int rl = lane >> 2, q = lane & 3;
    int m = mt * 16 + rl;
    float ss = 0.f;
    if (m < K_) {
      for (int p = q; p < P_; p += 4) { float v = C[m * P_ + p]; ss += v * v; }
    }
    ss += __shfl_xor(ss, 1);
    ss += __shfl_xor(ss, 2);
    if (q == 0) invn[rl] = 1.f / (sqrtf(ss) + 0.001f);
  }
  __syncthreads();
  int ml = lane & 15, quad = lane >> 4;
  int m = mt * 16 + ml;
  const float* src = (mat == 0) ? C : W2;
  short8v v8;
  #pragma unroll
  for (int j = 0; j < 8; ++j) {
    int k = ks * 32 + quad * 8 + j;
    float v = 0.f;
    if (m < K_ && k < P_) {
      v = src[m * P_ + k];
      if (mat == 0) v *= invn[ml];
    }
    v8[j] = f2bf(v);
  }
  *(short8v*)(apack + (size_t)(((mat * 4 + mt) * 10 + ks) * 512 + lane * 8)) = v8;
}

// ---------------------------------------------------------------------------
// K2 (fused GEMM + conv): per (b, 64-s chunk) with +-8 s halo:
//   stage 80 emb rows -> LDS bf16 (f32 norms en route; out-of-range s = 0)
//   dual GEMM via 16x16x32 bf16 MFMA:
//     G[m, 0..80)  = l_hat . x          (5 N-tiles, kept in registers)
//     Y[m, 8..72)  = W2 . x             (4 N-tiles -> Yt global, central 64 s)
//   then G*scale -> LDS (recycled xt space), 11-tap conv + relu + max over k,
//   write m[b, s0..s0+64) only. G never goes to global memory.
// grid 512 x 256. Wave w owns M-rows [16w,16w+16).
// LDS: xt 55.0 KB (reused as 64x81 f32 G-tile) + scale 320B + mpart 1KB
//      -> 2 blocks/CU (512 blocks / 256 CUs = exact fit).
// ---------------------------------------------------------------------------
__global__ __launch_bounds__(256) void k2_gemm(const int* __restrict__ idx,
                                               const float* __restrict__ emb,
                                               const short* __restrict__ apack,
                                               short* __restrict__ Yt,
                                               const float* __restrict__ conv_w,
                                               const float* __restrict__ conv_b,
                                               float* __restrict__ mbuf) {
  __shared__ __align__(16) char smem_raw[NS * LDX * 2];  // 55040 B
  __shared__ float scale_s[NS];
  __shared__ float mpart[4][64];
  short (*xt)[LDX]  = (short(*)[LDX])smem_raw;
  float (*gs)[LDGS] = (float(*)[LDGS])smem_raw;  // recycled after MFMA phase

  int bid = blockIdx.x;
  int b = bid >> 3, s0 = (bid & 7) * 64;
  int tid = threadIdx.x;
  int w = tid >> 6, lane = tid & 63;

  // stage: wave w loads staged rows [20w, 20w+20); staged row ls <-> s = s0-8+ls
  float ssr[20];
  #pragma unroll
  for (int r = 0; r < 20; ++r) {
    int ls = w * 20 + r;
    int sg = s0 - 8 + ls;
    float ss = 0.f;
    if (sg >= 0 && sg < S_) {
      int row = idx[b * S_ + sg];
      const float4* src = (const float4*)(emb + (size_t)row * P_);
      float4 v = src[lane];                       // p = 4*lane .. 4*lane+3 (p<256)
      ss = v.x * v.x + v.y * v.y + v.z * v.z + v.w * v.w;
      short4 h; h.x = f2bf(v.x); h.y = f2bf(v.y); h.z = f2bf(v.z); h.w = f2bf(v.w);
      *(short4*)&xt[ls][4 * lane] = h;
      if (lane < 11) {                            // p = 256..299
        float4 v2 = src[64 + lane];
        ss += v2.x * v2.x + v2.y * v2.y + v2.z * v2.z + v2.w * v2.w;
        short4 h2; h2.x = f2bf(v2.x); h2.y = f2bf(v2.y); h2.z = f2bf(v2.z); h2.w = f2bf(v2.w);
        *(short4*)&xt[ls][256 + 4 * lane] = h2;
      } else if (lane < 16) {                     // zero K-pad cols 300..319
        short4 z = {0, 0, 0, 0};
        *(short4*)&xt[ls][300 + 4 * (lane - 11)] = z;
      }
    } else {                                      // out-of-range s: zero row (G col = 0)
      short4 z = {0, 0, 0, 0};
      *(short4*)&xt[ls][4 * lane] = z;
      if (lane < 11)       *(short4*)&xt[ls][256 + 4 * lane] = z;
      else if (lane < 16)  *(short4*)&xt[ls][300 + 4 * (lane - 11)] = z;
    }
    ssr[r] = ss;
  }
  #pragma unroll
  for (int r = 0; r < 20; ++r) {
    float ss = ssr[r];
    #pragma unroll
    for (int off = 32; off > 0; off >>= 1) ss += __shfl_xor(ss, off);
    if (lane == 0) scale_s[w * 20 + r] = 1.f / (sqrtf(ss) + 0.001f);
  }
  __syncthreads();

  float4v accG[5] = {};   // G over staged cols 0..80 (5 tiles)
  float4v accY[4] = {};   // Y over staged cols 8..72 (central 64 s)
  int ml = lane & 15, quad = lane >> 4;
  const short8v* a1p = (const short8v*)(apack) + (size_t)((0 * 4 + w) * 10) * 64 + lane;
  const short8v* a2p = (const short8v*)(apack) + (size_t)((1 * 4 + w) * 10) * 64 + lane;
  #pragma unroll
  for (int ks = 0; ks < 10; ++ks) {
    short8v a1 = a1p[ks * 64];
    short8v a2 = a2p[ks * 64];
    int kk = ks * 32 + quad * 8;
    #pragma unroll
    for (int nt = 0; nt < 5; ++nt) {
      short8v bg = *(const short8v*)&xt[nt * 16 + ml][kk];
      accG[nt] = __builtin_amdgcn_mfma_f32_16x16x32_bf16(a1, bg, accG[nt], 0, 0, 0);
    }
    #pragma unroll
    for (int nt = 0; nt < 4; ++nt) {
      short8v by = *(const short8v*)&xt[8 + nt * 16 + ml][kk];
      accY[nt] = __builtin_amdgcn_mfma_f32_16x16x32_bf16(a2, by, accY[nt], 0, 0, 0);
    }
  }

  // Yt epilogue (register-only; before xt space is recycled)
  // C/D layout: col = lane&15 (-> s), row = quad*4+reg (-> m)
  #pragma unroll
  for (int nt = 0; nt < 4; ++nt) {
    int sg = s0 + nt * 16 + ml;
    #pragma unroll
    for (int reg = 0; reg < 4; ++reg) {
      int m = w * 16 + quad * 4 + reg;
      if (m < K_) Yt[(size_t)(b * MPAD + m) * S_ + sg] = f2bf(accY[nt][reg]);
    }
  }

  // conv weights (uniform -> scalar loads)
  float wvv[11];
  #pragma unroll
  for (int t = 0; t < 11; ++t) wvv[t] = conv_w[t];
  float cb = conv_b[0];

  __syncthreads();  // all waves done reading xt -> safe to recycle as gs

  // scaled G tile -> LDS: gs[m][scol], scol in [0,80)
  #pragma unroll
  for (int nt = 0; nt < 5; ++nt) {
    int scol = nt * 16 + ml;
    float sc = scale_s[scol];
    #pragma unroll
    for (int reg = 0; reg < 4; ++reg) {
      int m = w * 16 + quad * 4 + reg;
      gs[m][scol] = accG[nt][reg] * sc;
    }
  }
  __syncthreads();

  // conv + relu + max over k. thread = (sloc = lane, kgroup = w).
  // center s = s0 + sloc <-> staged index sloc+8; window taps at sloc+3 .. sloc+13.
  float part = 0.f;  // relu >= 0, safe identity
  for (int k = w; k < K_; k += 4) {
    float acc = cb;
    #pragma unroll
    for (int t = 0; t < 11; ++t) acc += wvv[t] * gs[k][lane + 3 + t];
    part = fmaxf(part, fmaxf(acc, 0.f));
  }
  mpart[w][lane] = part;
  __syncthreads();
  if (tid < 64) {
    float m0 = fmaxf(fmaxf(mpart[0][tid], mpart[1][tid]),
                     fmaxf(mpart[2][tid], mpart[3][tid]));
    mbuf[b * S_ + s0 + tid] = m0;
  }
}

// ---------------------------------------------------------------------------
// K3 (light): one block per b (512 threads). Reads m[b,s] (2 KB), softmax,
// then out[b,k] = sum_s beta[s]*Yt[b,k,s] + b2[k] (wave per k).
// LDS ~2 KB -> high occupancy; the conv/stage phase is gone (fused into K2).
// ---------------------------------------------------------------------------
__global__ __launch_bounds__(512) void k3_pool(const float* __restrict__ mbuf,
                                               const short* __restrict__ Yt,
                                               const float* __restrict__ b2,
                                               float* __restrict__ out) {
  __shared__ float beta[S_];
  __shared__ float red[8];
  int b = blockIdx.x;
  int tid = threadIdx.x;
  int lane = tid & 63, wv = tid >> 6;

  float mx = mbuf[b * S_ + tid];

  // block softmax over s (512 threads)
  float r = mx;
  #pragma unroll
  for (int off = 32; off > 0; off >>= 1) r = fmaxf(r, __shfl_xor(r, off));
  if (lane == 0) red[wv] = r;
  __syncthreads();
  float bm = red[0];
  #pragma unroll
  for (int i = 1; i < 8; ++i) bm = fmaxf(bm, red[i]);
  float e = __expf(mx - bm);
  r = e;
  #pragma unroll
  for (int off = 32; off > 0; off >>= 1) r += __shfl_xor(r, off);
  __syncthreads();               // everyone done reading red (max) before rewrite
  if (lane == 0) red[wv] = r;
  __syncthreads();
  float sum = 0.f;
  #pragma unroll
  for (int i = 0; i < 8; ++i) sum += red[i];
  beta[tid] = e / (sum * (float)S_);   // fold 1/S of jnp.mean into beta
  __syncthreads();

  // out[b,k] = sum_s beta[s] * Yt[b,k,s] + b2[k]; wave wv handles k = wv, wv+8, ...
  for (int k = wv; k < K_; k += 8) {
    short8v y = *(const short8v*)(Yt + (((size_t)(b * MPAD + k)) << 9) + lane * 8);
    const float4* bp = (const float4*)&beta[lane * 8];
    float4 b0 = bp[0], b1 = bp[1];
    float acc = b0.x * bf2f(y[0]) + b0.y * bf2f(y[1]) +
                b0.z * bf2f(y[2]) + b0.w * bf2f(y[3]) +
                b1.x * bf2f(y[4]) + b1.y * bf2f(y[5]) +
                b1.z * bf2f(y[6]) + b1.w * bf2f(y[7]);
    #pragma unroll
    for (int off = 32; off > 0; off >>= 1) acc += __shfl_xor(acc, off);
    if (lane == 0) out[b * K_ + k] = acc + b2[k];
  }
}

// ---------------------------------------------------------------------------
extern "C" void kernel_launch(void* const* d_in, const int* in_sizes, int n_in,
                              void* d_out, int out_size, void* d_ws, size_t ws_size,
                              hipStream_t stream) {
  const int*   idx    = (const int*)  d_in[0];
  const float* emb    = (const float*)d_in[1];
  const float* C      = (const float*)d_in[2];
  const float* conv_w = (const float*)d_in[3];
  const float* conv_b = (const float*)d_in[4];
  const float* W2     = (const float*)d_in[5];
  const float* b2     = (const float*)d_in[6];
  float* out = (float*)d_out;

  char* ws = (char*)d_ws;
  // ws layout (bytes): apack 81920 | Yt bf16 4 MiB | mbuf f32 128 KiB
  short* apack = (short*)(ws);
  short* Yt    = (short*)(ws + 81920);
  float* mbuf  = (float*)(ws + 81920 + 4194304);

  hipLaunchKernelGGL(k1_prep, dim3(80),  dim3(64),  0, stream, C, W2, apack);
  hipLaunchKernelGGL(k2_gemm, dim3(512), dim3(256), 0, stream,
                     idx, emb, apack, Yt, conv_w, conv_b, mbuf);
  hipLaunchKernelGGL(k3_pool, dim3(64),  dim3(512), 0, stream, mbuf, Yt, b2, out);
}

// Round 2
// 144.936 us; speedup vs baseline: 1.0888x; 1.0888x over previous
//
#include <hip/hip_runtime.h>

// Problem constants (fixed by the reference)
#define B_   64
#define S_   512
#define P_   300
#define K_   50
#define MPAD 64      // label dim padded to 64 for MFMA M
#define LDX  344     // x_tile row stride in bf16 elems (16B-aligned rows, bank-balanced)
#define NS   80      // staged s rows per block: 64 + 2*8 halo (5 MFMA N-tiles)
#define LDM  67      // transposed G-tile stride in floats: odd, 3*l mod 32 spreads banks

typedef short short8v __attribute__((ext_vector_type(8)));
typedef float float4v __attribute__((ext_vector_type(4)));

__device__ __forceinline__ short f2bf(float f) {
  unsigned u = __builtin_bit_cast(unsigned, f);
  u = (u + 0x7FFFu + ((u >> 16) & 1u)) >> 16;  // RNE
  return (short)u;
}
__device__ __forceinline__ float bf2f(short h) {
  return __builtin_bit_cast(float, ((unsigned)(unsigned short)h) << 16);
}

// ---------------------------------------------------------------------------
// K1: normalize C -> l_hat, pad {l_hat, W2} to 64x320 bf16 (zeros), and pack
// into MFMA A-fragment order so K2's A loads are coalesced 16B/lane.
// apack layout: [(mat*4 + mtile)*10 + kstep][lane][8 bf16]
// ---------------------------------------------------------------------------
__global__ __launch_bounds__(64) void k1_prep(const float* __restrict__ C,
                                              const float* __restrict__ W2,
                                              short* __restrict__ apack) {
  int bid = blockIdx.x;
  int mat = bid / 40;
  int rem = bid - mat * 40;
  int mt  = rem / 10;
  int ks  = rem - mt * 10;
  int lane = threadIdx.x;
  __shared__ float invn[16];
  if (mat == 0) {
    int rl = lane >> 2, q = lane & 3;
    int m = mt * 16 + rl;
    float ss = 0.f;
    if (m < K_) {
      for (int p = q; p < P_; p += 4) { float v = C[m * P_ + p]; ss += v * v; }
    }
    ss += __shfl_xor(ss, 1);
    ss += __shfl_xor(ss, 2);
    if (q == 0) invn[rl] = 1.f / (sqrtf(ss) + 0.001f);
  }
  __syncthreads();
  int ml = lane & 15, quad = lane >> 4;
  int m = mt * 16 + ml;
  const float* src = (mat == 0) ? C : W2;
  short8v v8;
  #pragma unroll
  for (int j = 0; j < 8; ++j) {
    int k = ks * 32 + quad * 8 + j;
    float v = 0.f;
    if (m < K_ && k < P_) {
      v = src[m * P_ + k];
      if (mat == 0) v *= invn[ml];
    }
    v8[j] = f2bf(v);
  }
  *(short8v*)(apack + (size_t)(((mat * 4 + mt) * 10 + ks) * 512 + lane * 8)) = v8;
}

// ---------------------------------------------------------------------------
// K2 (fused GEMM + conv), latency-optimized stage:
//   - scalar (wave-uniform) idx loads upfront  -> no per-row dependent chain
//   - emb gathers in 2 batches of 10 rows, all loads issued before converts
//     (launch_bounds(256,2) -> 256 VGPR budget, 20 loads in flight per wave)
//   - A-fragments prefetched to registers before the barrier
//   - conv tile transposed to gst[s][k], stride 67 (conflict-free r/w)
// grid 512 x 256, 2 blocks/CU (LDS 56.4 KB).
// ---------------------------------------------------------------------------
__global__ __launch_bounds__(256, 2) void k2_gemm(const int* __restrict__ idx,
                                                  const float* __restrict__ emb,
                                                  const short* __restrict__ apack,
                                                  short* __restrict__ Yt,
                                                  const float* __restrict__ conv_w,
                                                  const float* __restrict__ conv_b,
                                                  float* __restrict__ mbuf) {
  __shared__ __align__(16) char smem_raw[NS * LDX * 2];  // 55040 B
  __shared__ float scale_s[NS];
  __shared__ float mpart[4][64];
  short (*xt)[LDX] = (short(*)[LDX])smem_raw;
  float (*gst)[LDM] = (float(*)[LDM])smem_raw;  // recycled: [80 s][67] transposed G

  int bid = blockIdx.x;
  int b = bid >> 3, s0 = (bid & 7) * 64;
  int tid = threadIdx.x;
  int lane = tid & 63;
  int wu = __builtin_amdgcn_readfirstlane(tid >> 6);  // wave id as SGPR

  // --- scalar row indices (uniform addresses -> s_load, all independent) ---
  int rows[20];
  #pragma unroll
  for (int r = 0; r < 20; ++r) {
    int sg = s0 - 8 + wu * 20 + r;
    int sgc = sg < 0 ? 0 : (sg >= S_ ? S_ - 1 : sg);
    rows[r] = idx[b * S_ + sgc];
  }

  // --- gather: 2 batches of 10 rows, loads issued before converts ---
  float ssr[20];
  #pragma unroll
  for (int h = 0; h < 2; ++h) {
    float4 va[10], vb[10];
    #pragma unroll
    for (int r = 0; r < 10; ++r) {
      const float4* src = (const float4*)(emb + (size_t)rows[h * 10 + r] * P_);
      va[r] = src[lane];                 // p = 4*lane .. 4*lane+3 (p<256)
      if (lane < 11) vb[r] = src[64 + lane];  // p = 256..299
    }
    #pragma unroll
    for (int r = 0; r < 10; ++r) {
      int ls = wu * 20 + h * 10 + r;
      int sg = s0 - 8 + ls;
      bool oob = (sg < 0) || (sg >= S_);
      float4 v = va[r];
      if (oob) { v.x = 0.f; v.y = 0.f; v.z = 0.f; v.w = 0.f; }
      float ss = v.x * v.x + v.y * v.y + v.z * v.z + v.w * v.w;
      short4 hh; hh.x = f2bf(v.x); hh.y = f2bf(v.y); hh.z = f2bf(v.z); hh.w = f2bf(v.w);
      *(short4*)&xt[ls][4 * lane] = hh;
      if (lane < 11) {
        float4 v2 = vb[r];
        if (oob) { v2.x = 0.f; v2.y = 0.f; v2.z = 0.f; v2.w = 0.f; }
        ss += v2.x * v2.x + v2.y * v2.y + v2.z * v2.z + v2.w * v2.w;
        short4 h2; h2.x = f2bf(v2.x); h2.y = f2bf(v2.y); h2.z = f2bf(v2.z); h2.w = f2bf(v2.w);
        *(short4*)&xt[ls][256 + 4 * lane] = h2;
      } else if (lane < 16) {            // zero K-pad cols 300..319
        short4 z = {0, 0, 0, 0};
        *(short4*)&xt[ls][300 + 4 * (lane - 11)] = z;
      }
      ssr[h * 10 + r] = ss;
    }
  }
  #pragma unroll
  for (int r = 0; r < 20; ++r) {
    float ss = ssr[r];
    #pragma unroll
    for (int off = 32; off > 0; off >>= 1) ss += __shfl_xor(ss, off);
    if (lane == 0) scale_s[wu * 20 + r] = 1.f / (sqrtf(ss) + 0.001f);
  }

  // --- prefetch all A-fragments to registers (L2-hot, overlaps barrier) ---
  const short8v* a1p = (const short8v*)(apack) + (size_t)((0 * 4 + wu) * 10) * 64 + lane;
  const short8v* a2p = (const short8v*)(apack) + (size_t)((1 * 4 + wu) * 10) * 64 + lane;
  short8v a1f[10], a2f[10];
  #pragma unroll
  for (int ks = 0; ks < 10; ++ks) { a1f[ks] = a1p[ks * 64]; a2f[ks] = a2p[ks * 64]; }

  __syncthreads();

  // --- dual GEMM ---
  float4v accG[5] = {};   // G over staged cols 0..80 (5 tiles)
  float4v accY[4] = {};   // Y over staged cols 8..72 (central 64 s)
  int ml = lane & 15, quad = lane >> 4;
  #pragma unroll
  for (int ks = 0; ks < 10; ++ks) {
    int kk = ks * 32 + quad * 8;
    #pragma unroll
    for (int nt = 0; nt < 5; ++nt) {
      short8v bg = *(const short8v*)&xt[nt * 16 + ml][kk];
      accG[nt] = __builtin_amdgcn_mfma_f32_16x16x32_bf16(a1f[ks], bg, accG[nt], 0, 0, 0);
    }
    #pragma unroll
    for (int nt = 0; nt < 4; ++nt) {
      short8v by = *(const short8v*)&xt[8 + nt * 16 + ml][kk];
      accY[nt] = __builtin_amdgcn_mfma_f32_16x16x32_bf16(a2f[ks], by, accY[nt], 0, 0, 0);
    }
  }

  // --- Yt epilogue (register-only). C/D: col = lane&15 (s), row = quad*4+reg (m)
  #pragma unroll
  for (int nt = 0; nt < 4; ++nt) {
    int sg = s0 + nt * 16 + ml;
    #pragma unroll
    for (int reg = 0; reg < 4; ++reg) {
      int m = wu * 16 + quad * 4 + reg;
      if (m < K_) Yt[(size_t)(b * MPAD + m) * S_ + sg] = f2bf(accY[nt][reg]);
    }
  }

  // conv weights (uniform -> scalar loads)
  float wvv[11];
  #pragma unroll
  for (int t = 0; t < 11; ++t) wvv[t] = conv_w[t];
  float cb = conv_b[0];

  __syncthreads();  // all waves done reading xt -> safe to recycle as gst

  // --- scaled G tile -> LDS transposed: gst[scol][m] ---
  #pragma unroll
  for (int nt = 0; nt < 5; ++nt) {
    int scol = nt * 16 + ml;
    float sc = scale_s[scol];
    #pragma unroll
    for (int reg = 0; reg < 4; ++reg) {
      int m = wu * 16 + quad * 4 + reg;
      gst[scol][m] = accG[nt][reg] * sc;
    }
  }
  __syncthreads();

  // --- conv + relu + max over k. thread = (s = lane, k-group = wu). ---
  // center s staged index = lane+8; taps at staged cols lane+3 .. lane+13.
  float part = 0.f;  // relu >= 0, safe identity
  for (int k = wu; k < K_; k += 4) {
    float acc = cb;
    #pragma unroll
    for (int t = 0; t < 11; ++t) acc += wvv[t] * gst[lane + 3 + t][k];
    part = fmaxf(part, fmaxf(acc, 0.f));
  }
  mpart[wu][lane] = part;
  __syncthreads();
  if (tid < 64) {
    float m0 = fmaxf(fmaxf(mpart[0][tid], mpart[1][tid]),
                     fmaxf(mpart[2][tid], mpart[3][tid]));
    mbuf[b * S_ + s0 + tid] = m0;
  }
}

// ---------------------------------------------------------------------------
// K3 (light): one block per b (512 threads). Reads m[b,s] (2 KB), softmax,
// then out[b,k] = sum_s beta[s]*Yt[b,k,s] + b2[k] (wave per k).
// ---------------------------------------------------------------------------
__global__ __launch_bounds__(512) void k3_pool(const float* __restrict__ mbuf,
                                               const short* __restrict__ Yt,
                                               const float* __restrict__ b2,
                                               float* __restrict__ out) {
  __shared__ float beta[S_];
  __shared__ float red[8];
  int b = blockIdx.x;
  int tid = threadIdx.x;
  int lane = tid & 63, wv = tid >> 6;

  float mx = mbuf[b * S_ + tid];

  // block softmax over s (512 threads)
  float r = mx;
  #pragma unroll
  for (int off = 32; off > 0; off >>= 1) r = fmaxf(r, __shfl_xor(r, off));
  if (lane == 0) red[wv] = r;
  __syncthreads();
  float bm = red[0];
  #pragma unroll
  for (int i = 1; i < 8; ++i) bm = fmaxf(bm, red[i]);
  float e = __expf(mx - bm);
  r = e;
  #pragma unroll
  for (int off = 32; off > 0; off >>= 1) r += __shfl_xor(r, off);
  __syncthreads();               // everyone done reading red (max) before rewrite
  if (lane == 0) red[wv] = r;
  __syncthreads();
  float sum = 0.f;
  #pragma unroll
  for (int i = 0; i < 8; ++i) sum += red[i];
  beta[tid] = e / (sum * (float)S_);   // fold 1/S of jnp.mean into beta
  __syncthreads();

  // out[b,k] = sum_s beta[s] * Yt[b,k,s] + b2[k]; wave wv handles k = wv, wv+8, ...
  for (int k = wv; k < K_; k += 8) {
    short8v y = *(const short8v*)(Yt + (((size_t)(b * MPAD + k)) << 9) + lane * 8);
    const float4* bp = (const float4*)&beta[lane * 8];
    float4 b0 = bp[0], b1 = bp[1];
    float acc = b0.x * bf2f(y[0]) + b0.y * bf2f(y[1]) +
                b0.z * bf2f(y[2]) + b0.w * bf2f(y[3]) +
                b1.x * bf2f(y[4]) + b1.y * bf2f(y[5]) +
                b1.z * bf2f(y[6]) + b1.w * bf2f(y[7]);
    #pragma unroll
    for (int off = 32; off > 0; off >>= 1) acc += __shfl_xor(acc, off);
    if (lane == 0) out[b * K_ + k] = acc + b2[k];
  }
}

// ---------------------------------------------------------------------------
extern "C" void kernel_launch(void* const* d_in, const int* in_sizes, int n_in,
                              void* d_out, int out_size, void* d_ws, size_t ws_size,
                              hipStream_t stream) {
  const int*   idx    = (const int*)  d_in[0];
  const float* emb    = (const float*)d_in[1];
  const float* C      = (const float*)d_in[2];
  const float* conv_w = (const float*)d_in[3];
  const float* conv_b = (const float*)d_in[4];
  const float* W2     = (const float*)d_in[5];
  const float* b2     = (const float*)d_in[6];
  float* out = (float*)d_out;

  char* ws = (char*)d_ws;
  // ws layout (bytes): apack 81920 | Yt bf16 4 MiB | mbuf f32 128 KiB
  short* apack = (short*)(ws);
  short* Yt    = (short*)(ws + 81920);
  float* mbuf  = (float*)(ws + 81920 + 4194304);

  hipLaunchKernelGGL(k1_prep, dim3(80),  dim3(64),  0, stream, C, W2, apack);
  hipLaunchKernelGGL(k2_gemm, dim3(512), dim3(256), 0, stream,
                     idx, emb, apack, Yt, conv_w, conv_b, mbuf);
  hipLaunchKernelGGL(k3_pool, dim3(64),  dim3(512), 0, stream, mbuf, Yt, b2, out);
}

// Round 4
// 142.920 us; speedup vs baseline: 1.1041x; 1.0141x over previous
//
#include <hip/hip_runtime.h>

// Problem constants (fixed by the reference)
#define B_   64
#define S_   512
#define P_   300
#define K_   50
#define MPAD 64      // label dim padded to 64 for MFMA M
#define LDX  344     // x_tile row stride in bf16 elems (16B-aligned rows, bank-balanced)
#define NS   48      // staged s rows per block: 32 + 2*8 halo (3 MFMA N-tiles)
#define SCH  32      // central s columns per block
#define LDM  67      // transposed G-tile stride in floats (odd; 3*l mod 32 spreads banks)

typedef short short8v __attribute__((ext_vector_type(8)));
typedef float float4v __attribute__((ext_vector_type(4)));

__device__ __forceinline__ short f2bf(float f) {
  unsigned u = __builtin_bit_cast(unsigned, f);
  u = (u + 0x7FFFu + ((u >> 16) & 1u)) >> 16;  // RNE
  return (short)u;
}
__device__ __forceinline__ float bf2f(short h) {
  return __builtin_bit_cast(float, ((unsigned)(unsigned short)h) << 16);
}

// ---------------------------------------------------------------------------
// K1: normalize C -> l_hat, pad {l_hat, W2} to 64x320 bf16 (zeros), and pack
// into MFMA A-fragment order so K2's A loads are coalesced 16B/lane.
// apack layout: [(mat*4 + mtile)*10 + kstep][lane][8 bf16]
// ---------------------------------------------------------------------------
__global__ __launch_bounds__(64) void k1_prep(const float* __restrict__ C,
                                              const float* __restrict__ W2,
                                              short* __restrict__ apack) {
  int bid = blockIdx.x;
  int mat = bid / 40;
  int rem = bid - mat * 40;
  int mt  = rem / 10;
  int ks  = rem - mt * 10;
  int lane = threadIdx.x;
  __shared__ float invn[16];
  if (mat == 0) {
    int rl = lane >> 2, q = lane & 3;
    int m = mt * 16 + rl;
    float ss = 0.f;
    if (m < K_) {
      for (int p = q; p < P_; p += 4) { float v = C[m * P_ + p]; ss += v * v; }
    }
    ss += __shfl_xor(ss, 1);
    ss += __shfl_xor(ss, 2);
    if (q == 0) invn[rl] = 1.f / (sqrtf(ss) + 0.001f);
  }
  __syncthreads();
  int ml = lane & 15, quad = lane >> 4;
  int m = mt * 16 + ml;
  const float* src = (mat == 0) ? C : W2;
  short8v v8;
  #pragma unroll
  for (int j = 0; j < 8; ++j) {
    int k = ks * 32 + quad * 8 + j;
    float v = 0.f;
    if (m < K_ && k < P_) {
      v = src[m * P_ + k];
      if (mat == 0) v *= invn[ml];
    }
    v8[j] = f2bf(v);
  }
  *(short8v*)(apack + (size_t)(((mat * 4 + mt) * 10 + ks) * 512 + lane * 8)) = v8;
}

// ---------------------------------------------------------------------------
// K2 (fused GEMM + conv), occupancy-optimized:
//   grid 1024 x 256: block = (b, 32-s chunk) with +-8 s halo (48 staged rows).
//   LDS 34.3 KB -> 4 blocks/CU by LDS; launch_bounds(256,3) -> 12-16 waves/CU
//   (2x round-2's 8). Per-wave critical path halves: 12 gathers, 50 MFMA.
//   - scalar (wave-uniform) idx loads upfront
//   - emb gathers in 2 batches of 6 rows, loads issued before converts
//   - A-fragments prefetched to registers before the barrier
//   - conv tile transposed gst[s][k], stride 67 (conflict-free)
// ---------------------------------------------------------------------------
__global__ __launch_bounds__(256, 3) void k2_gemm(const int* __restrict__ idx,
                                                  const float* __restrict__ emb,
                                                  const short* __restrict__ apack,
                                                  short* __restrict__ Yt,
                                                  const float* __restrict__ conv_w,
                                                  const float* __restrict__ conv_b,
                                                  float* __restrict__ mbuf) {
  __shared__ __align__(16) char smem_raw[NS * LDX * 2];  // 33024 B
  __shared__ float scale_s[NS];
  __shared__ float mpart[8][SCH];
  short (*xt)[LDX] = (short(*)[LDX])smem_raw;
  float (*gst)[LDM] = (float(*)[LDM])smem_raw;  // recycled: [48 s][67] transposed G

  int bid = blockIdx.x;
  int b = bid >> 4, s0 = (bid & 15) * SCH;
  int tid = threadIdx.x;
  int lane = tid & 63;
  int wu = __builtin_amdgcn_readfirstlane(tid >> 6);  // wave id as SGPR

  // --- scalar row indices (uniform addresses -> s_load, all independent) ---
  int rows[12];
  #pragma unroll
  for (int r = 0; r < 12; ++r) {
    int sg = s0 - 8 + wu * 12 + r;
    int sgc = sg < 0 ? 0 : (sg >= S_ ? S_ - 1 : sg);
    rows[r] = idx[b * S_ + sgc];
  }

  // --- gather: 2 batches of 6 rows, loads issued before converts ---
  float ssr[12];
  #pragma unroll
  for (int h = 0; h < 2; ++h) {
    float4 va[6], vb[6];
    #pragma unroll
    for (int r = 0; r < 6; ++r) {
      const float4* src = (const float4*)(emb + (size_t)rows[h * 6 + r] * P_);
      va[r] = src[lane];                      // p = 4*lane .. 4*lane+3 (p<256)
      if (lane < 11) vb[r] = src[64 + lane];  // p = 256..299
    }
    #pragma unroll
    for (int r = 0; r < 6; ++r) {
      int ls = wu * 12 + h * 6 + r;
      int sg = s0 - 8 + ls;
      bool oob = (sg < 0) || (sg >= S_);
      float4 v = va[r];
      if (oob) { v.x = 0.f; v.y = 0.f; v.z = 0.f; v.w = 0.f; }
      float ss = v.x * v.x + v.y * v.y + v.z * v.z + v.w * v.w;
      short4 hh; hh.x = f2bf(v.x); hh.y = f2bf(v.y); hh.z = f2bf(v.z); hh.w = f2bf(v.w);
      *(short4*)&xt[ls][4 * lane] = hh;
      if (lane < 11) {
        float4 v2 = vb[r];
        if (oob) { v2.x = 0.f; v2.y = 0.f; v2.z = 0.f; v2.w = 0.f; }
        ss += v2.x * v2.x + v2.y * v2.y + v2.z * v2.z + v2.w * v2.w;
        short4 h2; h2.x = f2bf(v2.x); h2.y = f2bf(v2.y); h2.z = f2bf(v2.z); h2.w = f2bf(v2.w);
        *(short4*)&xt[ls][256 + 4 * lane] = h2;
      } else if (lane < 16) {                 // zero K-pad cols 300..319
        short4 z = {0, 0, 0, 0};
        *(short4*)&xt[ls][300 + 4 * (lane - 11)] = z;
      }
      ssr[h * 6 + r] = ss;
    }
  }
  #pragma unroll
  for (int r = 0; r < 12; ++r) {
    float ss = ssr[r];
    #pragma unroll
    for (int off = 32; off > 0; off >>= 1) ss += __shfl_xor(ss, off);
    if (lane == 0) scale_s[wu * 12 + r] = 1.f / (sqrtf(ss) + 0.001f);
  }

  // --- prefetch all A-fragments to registers (L2-hot, overlaps barrier) ---
  const short8v* a1p = (const short8v*)(apack) + (size_t)((0 * 4 + wu) * 10) * 64 + lane;
  const short8v* a2p = (const short8v*)(apack) + (size_t)((1 * 4 + wu) * 10) * 64 + lane;
  short8v a1f[10], a2f[10];
  #pragma unroll
  for (int ks = 0; ks < 10; ++ks) { a1f[ks] = a1p[ks * 64]; a2f[ks] = a2p[ks * 64]; }

  __syncthreads();

  // --- dual GEMM: G over staged cols 0..48 (3 tiles), Y over central 32 (2) ---
  float4v accG[3] = {};
  float4v accY[2] = {};
  int ml = lane & 15, quad = lane >> 4;
  #pragma unroll
  for (int ks = 0; ks < 10; ++ks) {
    int kk = ks * 32 + quad * 8;
    #pragma unroll
    for (int nt = 0; nt < 3; ++nt) {
      short8v bg = *(const short8v*)&xt[nt * 16 + ml][kk];
      accG[nt] = __builtin_amdgcn_mfma_f32_16x16x32_bf16(a1f[ks], bg, accG[nt], 0, 0, 0);
    }
    #pragma unroll
    for (int nt = 0; nt < 2; ++nt) {
      short8v by = *(const short8v*)&xt[8 + nt * 16 + ml][kk];
      accY[nt] = __builtin_amdgcn_mfma_f32_16x16x32_bf16(a2f[ks], by, accY[nt], 0, 0, 0);
    }
  }

  // --- Yt epilogue (register-only). C/D: col = lane&15 (s), row = quad*4+reg (m)
  #pragma unroll
  for (int nt = 0; nt < 2; ++nt) {
    int sg = s0 + nt * 16 + ml;
    #pragma unroll
    for (int reg = 0; reg < 4; ++reg) {
      int m = wu * 16 + quad * 4 + reg;
      if (m < K_) Yt[(size_t)(b * MPAD + m) * S_ + sg] = f2bf(accY[nt][reg]);
    }
  }

  // conv weights (uniform -> scalar loads)
  float wvv[11];
  #pragma unroll
  for (int t = 0; t < 11; ++t) wvv[t] = conv_w[t];
  float cb = conv_b[0];

  __syncthreads();  // all waves done reading xt -> safe to recycle as gst

  // --- scaled G tile -> LDS transposed: gst[scol][m] ---
  #pragma unroll
  for (int nt = 0; nt < 3; ++nt) {
    int scol = nt * 16 + ml;
    float sc = scale_s[scol];
    #pragma unroll
    for (int reg = 0; reg < 4; ++reg) {
      int m = wu * 16 + quad * 4 + reg;
      gst[scol][m] = accG[nt][reg] * sc;
    }
  }
  __syncthreads();

  // --- conv + relu + max over k. thread = (s = tid&31, k-group = tid>>5). ---
  // center s staged index = sl+8; taps at staged cols sl+3 .. sl+13 (max 44 < 48).
  int sl = tid & 31, kg = tid >> 5;
  float part = 0.f;  // relu >= 0, safe identity
  for (int k = kg; k < K_; k += 8) {
    float acc = cb;
    #pragma unroll
    for (int t = 0; t < 11; ++t) acc += wvv[t] * gst[sl + 3 + t][k];
    part = fmaxf(part, fmaxf(acc, 0.f));
  }
  mpart[kg][sl] = part;
  __syncthreads();
  if (tid < SCH) {
    float m0 = mpart[0][tid];
    #pragma unroll
    for (int i = 1; i < 8; ++i) m0 = fmaxf(m0, mpart[i][tid]);
    mbuf[b * S_ + s0 + tid] = m0;
  }
}

// ---------------------------------------------------------------------------
// K3 (light): one block per b (512 threads). Reads m[b,s] (2 KB), softmax,
// then out[b,k] = sum_s beta[s]*Yt[b,k,s] + b2[k] (wave per k).
// ---------------------------------------------------------------------------
__global__ __launch_bounds__(512) void k3_pool(const float* __restrict__ mbuf,
                                               const short* __restrict__ Yt,
                                               const float* __restrict__ b2,
                                               float* __restrict__ out) {
  __shared__ float beta[S_];
  __shared__ float red[8];
  int b = blockIdx.x;
  int tid = threadIdx.x;
  int lane = tid & 63, wv = tid >> 6;

  float mx = mbuf[b * S_ + tid];

  // block softmax over s (512 threads)
  float r = mx;
  #pragma unroll
  for (int off = 32; off > 0; off >>= 1) r = fmaxf(r, __shfl_xor(r, off));
  if (lane == 0) red[wv] = r;
  __syncthreads();
  float bm = red[0];
  #pragma unroll
  for (int i = 1; i < 8; ++i) bm = fmaxf(bm, red[i]);
  float e = __expf(mx - bm);
  r = e;
  #pragma unroll
  for (int off = 32; off > 0; off >>= 1) r += __shfl_xor(r, off);
  __syncthreads();               // everyone done reading red (max) before rewrite
  if (lane == 0) red[wv] = r;
  __syncthreads();
  float sum = 0.f;
  #pragma unroll
  for (int i = 0; i < 8; ++i) sum += red[i];
  beta[tid] = e / (sum * (float)S_);   // fold 1/S of jnp.mean into beta
  __syncthreads();

  // out[b,k] = sum_s beta[s] * Yt[b,k,s] + b2[k]; wave wv handles k = wv, wv+8, ...
  for (int k = wv; k < K_; k += 8) {
    short8v y = *(const short8v*)(Yt + (((size_t)(b * MPAD + k)) << 9) + lane * 8);
    const float4* bp = (const float4*)&beta[lane * 8];
    float4 b0 = bp[0], b1 = bp[1];
    float acc = b0.x * bf2f(y[0]) + b0.y * bf2f(y[1]) +
                b0.z * bf2f(y[2]) + b0.w * bf2f(y[3]) +
                b1.x * bf2f(y[4]) + b1.y * bf2f(y[5]) +
                b1.z * bf2f(y[6]) + b1.w * bf2f(y[7]);
    #pragma unroll
    for (int off = 32; off > 0; off >>= 1) acc += __shfl_xor(acc, off);
    if (lane == 0) out[b * K_ + k] = acc + b2[k];
  }
}

// ---------------------------------------------------------------------------
extern "C" void kernel_launch(void* const* d_in, const int* in_sizes, int n_in,
                              void* d_out, int out_size, void* d_ws, size_t ws_size,
                              hipStream_t stream) {
  const int*   idx    = (const int*)  d_in[0];
  const float* emb    = (const float*)d_in[1];
  const float* C      = (const float*)d_in[2];
  const float* conv_w = (const float*)d_in[3];
  const float* conv_b = (const float*)d_in[4];
  const float* W2     = (const float*)d_in[5];
  const float* b2     = (const float*)d_in[6];
  float* out = (float*)d_out;

  char* ws = (char*)d_ws;
  // ws layout (bytes): apack 81920 | Yt bf16 4 MiB | mbuf f32 128 KiB
  short* apack = (short*)(ws);
  short* Yt    = (short*)(ws + 81920);
  float* mbuf  = (float*)(ws + 81920 + 4194304);

  hipLaunchKernelGGL(k1_prep, dim3(80),   dim3(64),  0, stream, C, W2, apack);
  hipLaunchKernelGGL(k2_gemm, dim3(1024), dim3(256), 0, stream,
                     idx, emb, apack, Yt, conv_w, conv_b, mbuf);
  hipLaunchKernelGGL(k3_pool, dim3(64),   dim3(512), 0, stream, mbuf, Yt, b2, out);
}